// Round 1
// baseline (1002.522 us; speedup 1.0000x reference)
//
#include <hip/hip_runtime.h>
#include <hip/hip_bf16.h>

typedef unsigned int u32;
typedef unsigned short u16;

#define DIMN 256
#define TLEN 256

// ---------------------------------------------------------------------------
// helpers
// ---------------------------------------------------------------------------
typedef _Float16 half2v __attribute__((ext_vector_type(2)));
typedef _Float16 f16x8  __attribute__((ext_vector_type(8)));
typedef float    f32x4  __attribute__((ext_vector_type(4)));

__device__ __forceinline__ u32 packh2(float lo, float hi) {
    _Float16 l = (_Float16)lo, h = (_Float16)hi;
    u16 lu = __builtin_bit_cast(u16, l);
    u16 hu = __builtin_bit_cast(u16, h);
    return (u32)lu | ((u32)hu << 16);
}

__device__ __forceinline__ float h2lo(u32 v) {
    return (float)__builtin_bit_cast(half2v, v).x;
}
__device__ __forceinline__ float h2hi(u32 v) {
    return (float)__builtin_bit_cast(half2v, v).y;
}

// ---------------------------------------------------------------------------
// prep kernels: build P^T, S^T, W^T (fp32), then pack S/P as MFMA A-fragments
//   Pt[j*256+i] = P[i][j],  P = D^T F D
//   St[j*256+i] = S[i][j],  S = I - (1/a) D^T (A^T A + lam2 I) D
//   Wt[d*256+i] = W[i][d],  W = (1/a) D^T A^T A
// ---------------------------------------------------------------------------
__global__ void prep1(const float* __restrict__ A, const float* __restrict__ D,
                      const float* __restrict__ F, const float* __restrict__ lam2p,
                      float* __restrict__ FD, float* __restrict__ G,
                      float* __restrict__ AD) {
    int gid = blockIdx.x * 256 + threadIdx.x;
    if (gid < 65536) {                   // FD[k][j] = sum_q F[k][q] D[q][j]
        int k = gid >> 8, j = gid & 255;
        float s = 0.f;
        #pragma unroll 8
        for (int q = 0; q < 256; ++q) s += F[k*256+q] * D[q*256+j];
        FD[gid] = s;
    } else if (gid < 131072) {           // G[p][q] = sum_m A[m][p] A[m][q] + lam2*(p==q)
        int g = gid - 65536; int p = g >> 8, q = g & 255;
        float s = (p == q) ? lam2p[0] : 0.f;
        #pragma unroll 8
        for (int m = 0; m < 64; ++m) s += A[m*256+p] * A[m*256+q];
        G[g] = s;
    } else if (gid < 147456) {           // AD[m][i] = sum_k A[m][k] D[k][i]
        int g = gid - 131072; int m = g >> 8, i = g & 255;
        float s = 0.f;
        #pragma unroll 8
        for (int k = 0; k < 256; ++k) s += A[m*256+k] * D[k*256+i];
        AD[g] = s;
    }
}

__global__ void prep2(const float* __restrict__ A, const float* __restrict__ D,
                      const float* __restrict__ alphap,
                      const float* __restrict__ FD, const float* __restrict__ G,
                      const float* __restrict__ AD,
                      float* __restrict__ Pt, float* __restrict__ GD,
                      float* __restrict__ Wt) {
    int gid = blockIdx.x * 256 + threadIdx.x;
    float inva = 1.0f / alphap[0];
    if (gid < 65536) {                   // Pt[j][i] = sum_k D[k][i] FD[k][j]
        int j = gid >> 8, i = gid & 255;
        float s = 0.f;
        #pragma unroll 8
        for (int k = 0; k < 256; ++k) s += D[k*256+i] * FD[k*256+j];
        Pt[gid] = s;
    } else if (gid < 131072) {           // GD[k][j] = sum_q G[k][q] D[q][j]
        int g = gid - 65536; int k = g >> 8, j = g & 255;
        float s = 0.f;
        #pragma unroll 8
        for (int q = 0; q < 256; ++q) s += G[k*256+q] * D[q*256+j];
        GD[g] = s;
    } else {                             // Wt[d][i] = inva * sum_m AD[m][i] A[m][d]
        int g = gid - 131072; int d = g >> 8, i = g & 255;
        float s = 0.f;
        #pragma unroll 8
        for (int m = 0; m < 64; ++m) s += AD[m*256+i] * A[m*256+d];
        Wt[g] = inva * s;
    }
}

__global__ void prep3(const float* __restrict__ D, const float* __restrict__ GD,
                      const float* __restrict__ alphap, float* __restrict__ St) {
    int gid = blockIdx.x * 256 + threadIdx.x;   // 65536 threads
    int j = gid >> 8, i = gid & 255;
    float inva = 1.0f / alphap[0];
    float s = 0.f;
    #pragma unroll 8
    for (int k = 0; k < 256; ++k) s += D[k*256+i] * GD[k*256+j];
    St[gid] = ((i == j) ? 1.0f : 0.0f) - inva * s;
}

// Pack S and P as fp16 MFMA A-fragments for v_mfma_f32_16x16x32_f16.
// Fragment (tile tau in 0..15, kk in 0..7, lane l):
//   8 fp16 = M[row][k0..k0+8) with row = 16*tau + (l&15), k0 = 32*kk + 8*(l>>4)
// stored as uint4 at Sfrag[((tau*8+kk)*64 + l)*4].
// (Any consistent k-permutation is fine: both A- and B-fragments are packed
//  by us, and the MFMA contraction is invariant under a shared k-perm.
//  S and P are symmetric, so A-side row/col orientation is also safe.)
__global__ void prep4(const float* __restrict__ St, const float* __restrict__ Pt,
                      u32* __restrict__ Sfrag, u32* __restrict__ Pfrag) {
    int gid = blockIdx.x * 256 + threadIdx.x;   // 16384 threads
    int idx = gid & 8191;
    int l   = idx & 63;
    int kk  = (idx >> 6) & 7;
    int tau = idx >> 9;
    int row = 16*tau + (l & 15);
    int k0  = 32*kk + 8*(l >> 4);
    const float* M = (gid < 8192) ? St : Pt;     // M[i][k] = Mt[k*256+i]
    u32* O = (gid < 8192) ? Sfrag : Pfrag;
    uint4 v;
    v.x = packh2(M[(k0+0)*256 + row], M[(k0+1)*256 + row]);
    v.y = packh2(M[(k0+2)*256 + row], M[(k0+3)*256 + row]);
    v.z = packh2(M[(k0+4)*256 + row], M[(k0+5)*256 + row]);
    v.w = packh2(M[(k0+6)*256 + row], M[(k0+7)*256 + row]);
    *(uint4*)&O[idx*4] = v;
}

// ---------------------------------------------------------------------------
// Z-GEMM: Z[b][t][i] = sum_d Wt[d*256+i] * y[b][d][t], written PACKED fp16:
//   Zh[(b*256+t)*128 + i/2] = (Z[b][t][i_even], Z[b][t][i_even+1])
// ---------------------------------------------------------------------------
__launch_bounds__(256, 2)
__global__ void zgemm(const float* __restrict__ y, const float* __restrict__ Wt,
                      u32* __restrict__ Zh) {
    __shared__ float ys[64][132];    // [dd][tt]
    __shared__ float wsh[64][132];   // [dd][ii]
    const int b  = blockIdx.x;
    const int t0 = (blockIdx.y & 1) * 128;
    const int i0 = (blockIdx.y >> 1) * 128;
    const int tid = threadIdx.x;
    const int tx = tid & 15;   // i-octet
    const int ty = tid >> 4;   // t-octet
    float acc[8][8];           // [c=t][a=i]
    #pragma unroll
    for (int c = 0; c < 8; ++c)
        #pragma unroll
        for (int a = 0; a < 8; ++a) acc[c][a] = 0.f;

    for (int dc = 0; dc < 256; dc += 64) {
        #pragma unroll
        for (int k = 0; k < 8; ++k) {
            int idx = k * 256 + tid;
            int row = idx >> 5, col4 = idx & 31;
            float4 yv = *(const float4*)&y[((size_t)b*256 + dc + row)*256 + t0 + col4*4];
            float4 wv = *(const float4*)&Wt[(size_t)(dc + row)*256 + i0 + col4*4];
            *(float4*)&ys[row][col4*4]  = yv;
            *(float4*)&wsh[row][col4*4] = wv;
        }
        __syncthreads();
        #pragma unroll 4
        for (int dd = 0; dd < 64; ++dd) {
            float4 w0 = *(const float4*)&wsh[dd][8*tx];
            float4 w1 = *(const float4*)&wsh[dd][8*tx+4];
            float4 y0 = *(const float4*)&ys[dd][8*ty];
            float4 y1 = *(const float4*)&ys[dd][8*ty+4];
            float wv[8] = {w0.x,w0.y,w0.z,w0.w,w1.x,w1.y,w1.z,w1.w};
            float yv[8] = {y0.x,y0.y,y0.z,y0.w,y1.x,y1.y,y1.z,y1.w};
            #pragma unroll
            for (int c = 0; c < 8; ++c)
                #pragma unroll
                for (int a = 0; a < 8; ++a) acc[c][a] += wv[a] * yv[c];
        }
        __syncthreads();
    }
    #pragma unroll
    for (int c = 0; c < 8; ++c) {
        int t = t0 + 8*ty + c;
        uint4 pk;
        pk.x = packh2(acc[c][0], acc[c][1]);
        pk.y = packh2(acc[c][2], acc[c][3]);
        pk.z = packh2(acc[c][4], acc[c][5]);
        pk.w = packh2(acc[c][6], acc[c][7]);
        *(uint4*)&Zh[((size_t)b*256 + t)*128 + (i0 >> 1) + 4*tx] = pk;
    }
}

// ---------------------------------------------------------------------------
// scan6: MFMA scan. 16 blocks x 512 threads; block = 16 batches, wave w owns
// output row-tiles {2w, 2w+1} (rows 32w..32w+31). Per iteration: 8 conflict-
// free ds_read_b128 of h B-fragments + 16 v_mfma_f32_16x16x32_f16 (S/P frags
// live in AGPRs, read natively by MFMA). const = Z + c2*Ph initializes the
// MFMA accumulator. h exchanged via double-buffered LDS laid out directly in
// B-fragment order (producer wave w owns K-slice kk=w). 5 barriers/step.
//
// D-layout per lane (verified m89): col(batch) = l&15, row = 16T + 4*(l>>4)+r.
// B-frag slot for h[k][b]: kk = k>>5, lane = ((k>>3)&3)*16 + b, word = (k&7)>>1.
// ---------------------------------------------------------------------------
__global__ __attribute__((amdgpu_flat_work_group_size(512, 512),
                          amdgpu_waves_per_eu(2, 2)))
void scan6(const u32* __restrict__ Sfrag, const u32* __restrict__ Pfrag,
           const u32* __restrict__ Zh,
           const float* __restrict__ h0, const float* __restrict__ U,
           const float* __restrict__ lam1p, const float* __restrict__ lam2p,
           const float* __restrict__ alphap,
           float* __restrict__ H) {
    __shared__ __align__(16) u32 hx[2 * 2048];   // 2 x 8 KB h B-fragment buffers

    const int tid = threadIdx.x;
    const int l   = tid & 63;
    const int w   = tid >> 6;          // wave 0..7
    const int lb  = l & 15;            // batch-in-group == MFMA col
    const int g   = l >> 4;            // 0..3
    const int b   = blockIdx.x * 16 + lb;

    const float inva = 1.0f / alphap[0];
    const float bt   = lam1p[0] * inva;
    const float c2   = lam2p[0] * inva;

    // per-lane rows: 32w + 16T + 4g + r
    const int rb = 32*w + 4*g;
    const float u00 = U[rb+0]*bt,  u01 = U[rb+1]*bt,  u02 = U[rb+2]*bt,  u03 = U[rb+3]*bt;
    const float u10 = U[rb+16]*bt, u11 = U[rb+17]*bt, u12 = U[rb+18]*bt, u13 = U[rb+19]*bt;

    // A-fragments -> (A)GPRs (coalesced uint4 loads)
    f16x8 Sf0[8], Sf1[8], Pf0[8], Pf1[8];
    #pragma unroll
    for (int kk = 0; kk < 8; ++kk) {
        Sf0[kk] = __builtin_bit_cast(f16x8, *(const uint4*)&Sfrag[(((2*w+0)*8 + kk)*64 + l)*4]);
        Sf1[kk] = __builtin_bit_cast(f16x8, *(const uint4*)&Sfrag[(((2*w+1)*8 + kk)*64 + l)*4]);
        Pf0[kk] = __builtin_bit_cast(f16x8, *(const uint4*)&Pfrag[(((2*w+0)*8 + kk)*64 + l)*4]);
        Pf1[kk] = __builtin_bit_cast(f16x8, *(const uint4*)&Pfrag[(((2*w+1)*8 + kk)*64 + l)*4]);
    }

    // init h_prev B-fragments (h0 is batch-independent: value depends on k only)
    {
        int k0 = 32*(tid >> 6) + 8*((tid & 63) >> 4);
        uint4 hv;
        hv.x = packh2(h0[k0+0], h0[k0+1]);
        hv.y = packh2(h0[k0+2], h0[k0+3]);
        hv.z = packh2(h0[k0+4], h0[k0+5]);
        hv.w = packh2(h0[k0+6], h0[k0+7]);
        *(uint4*)&hx[tid*4] = hv;
    }
    __syncthreads();

    // Z: uint2 at Zb[t*128 + 8T] covers i = 32w + 16T + 4g + {0..3}
    const u32* Zb = Zh + (size_t)b*32768 + 16*w + 2*g;
    float* Hb = H + (size_t)b*TLEN*DIMN + 32*w + 4*g;

    // write slot (u32 index inside a buffer) for this lane's tile-T=0 pair;
    // tile-T=1 is +128.  (kk = w slice; lane'' = (2T + (g>>1))*16 + lb)
    const int wb0 = w*256 + (((g>>1))*16 + lb)*4 + (g&1)*2;

    int ro = 0, wo = 2048;

    uint2 z0 = *(const uint2*)&Zb[0];
    uint2 z1 = *(const uint2*)&Zb[8];

    #pragma unroll 1
    for (int t = 0; t < TLEN; ++t) {
        const int tn = (t < TLEN-1) ? t + 1 : t;
        uint2 zn0 = *(const uint2*)&Zb[(size_t)tn*128];
        uint2 zn1 = *(const uint2*)&Zb[(size_t)tn*128 + 8];

        // ---- P-phase: ph = P @ h_prev ----
        f16x8 hb[8];
        #pragma unroll
        for (int kk = 0; kk < 8; ++kk)
            hb[kk] = __builtin_bit_cast(f16x8, *(const uint4*)&hx[ro + (kk*64 + l)*4]);
        f32x4 a0 = {0.f,0.f,0.f,0.f}, a1 = {0.f,0.f,0.f,0.f};
        #pragma unroll
        for (int kk = 0; kk < 8; ++kk) {
            a0 = __builtin_amdgcn_mfma_f32_16x16x32_f16(Pf0[kk], hb[kk], a0, 0, 0, 0);
            a1 = __builtin_amdgcn_mfma_f32_16x16x32_f16(Pf1[kk], hb[kk], a1, 0, 0, 0);
        }
        const float c00 = h2lo(z0.x) + c2*a0[0];
        const float c01 = h2hi(z0.x) + c2*a0[1];
        const float c02 = h2lo(z0.y) + c2*a0[2];
        const float c03 = h2hi(z0.y) + c2*a0[3];
        const float c10 = h2lo(z1.x) + c2*a1[0];
        const float c11 = h2hi(z1.x) + c2*a1[1];
        const float c12 = h2lo(z1.y) + c2*a1[2];
        const float c13 = h2hi(z1.y) + c2*a1[3];
        // h_iter0 = Ph (unthresholded)
        *(uint2*)&hx[wo + wb0]       = make_uint2(packh2(a0[0],a0[1]), packh2(a0[2],a0[3]));
        *(uint2*)&hx[wo + wb0 + 128] = make_uint2(packh2(a1[0],a1[1]), packh2(a1[2],a1[3]));
        __syncthreads();
        int rr = wo, ww = ro;

        // ---- 4 S-iterations: h = soft(S@h + const) ----
        #pragma unroll
        for (int it = 0; it < 4; ++it) {
            #pragma unroll
            for (int kk = 0; kk < 8; ++kk)
                hb[kk] = __builtin_bit_cast(f16x8, *(const uint4*)&hx[rr + (kk*64 + l)*4]);
            f32x4 s0 = {c00,c01,c02,c03};
            f32x4 s1 = {c10,c11,c12,c13};
            #pragma unroll
            for (int kk = 0; kk < 8; ++kk) {
                s0 = __builtin_amdgcn_mfma_f32_16x16x32_f16(Sf0[kk], hb[kk], s0, 0, 0, 0);
                s1 = __builtin_amdgcn_mfma_f32_16x16x32_f16(Sf1[kk], hb[kk], s1, 0, 0, 0);
            }
            float v, av;
            v = s0[0]; av = fabsf(v) - u00; const float h00 = (av > 0.f) ? copysignf(av, v) : 0.f;
            v = s0[1]; av = fabsf(v) - u01; const float h01 = (av > 0.f) ? copysignf(av, v) : 0.f;
            v = s0[2]; av = fabsf(v) - u02; const float h02 = (av > 0.f) ? copysignf(av, v) : 0.f;
            v = s0[3]; av = fabsf(v) - u03; const float h03 = (av > 0.f) ? copysignf(av, v) : 0.f;
            v = s1[0]; av = fabsf(v) - u10; const float h10 = (av > 0.f) ? copysignf(av, v) : 0.f;
            v = s1[1]; av = fabsf(v) - u11; const float h11 = (av > 0.f) ? copysignf(av, v) : 0.f;
            v = s1[2]; av = fabsf(v) - u12; const float h12 = (av > 0.f) ? copysignf(av, v) : 0.f;
            v = s1[3]; av = fabsf(v) - u13; const float h13 = (av > 0.f) ? copysignf(av, v) : 0.f;
            if (it == 3) {
                *(float2*)&Hb[(size_t)t*DIMN]      = make_float2(h00, h01);
                *(float2*)&Hb[(size_t)t*DIMN + 2]  = make_float2(h02, h03);
                *(float2*)&Hb[(size_t)t*DIMN + 16] = make_float2(h10, h11);
                *(float2*)&Hb[(size_t)t*DIMN + 18] = make_float2(h12, h13);
            }
            *(uint2*)&hx[ww + wb0]       = make_uint2(packh2(h00,h01), packh2(h02,h03));
            *(uint2*)&hx[ww + wb0 + 128] = make_uint2(packh2(h10,h11), packh2(h12,h13));
            __syncthreads();
            int tmp = rr; rr = ww; ww = tmp;
        }
        ro = rr; wo = ww;     // rr holds final h_t -> next step's h_prev
        z0 = zn0; z1 = zn1;
    }
}

// ---------------------------------------------------------------------------
// out-GEMM: out[b][n][t] = sum_d D[n][d] * H[b][t][d]
// ---------------------------------------------------------------------------
__launch_bounds__(256, 2)
__global__ void ogemm(const float* __restrict__ D, const float* __restrict__ H,
                      float* __restrict__ out) {
    __shared__ float Ds[64][132];   // [dd][nn]
    __shared__ float Hs[64][132];   // [dd][tt]
    const int b  = blockIdx.x;
    const int n0 = (blockIdx.y & 1) * 128;
    const int t0 = (blockIdx.y >> 1) * 128;
    const int tid = threadIdx.x;
    const int tx = tid & 15;   // n-octet
    const int ty = tid >> 4;   // t-octet
    float acc[8][8];           // [a=n][c=t]
    #pragma unroll
    for (int a = 0; a < 8; ++a)
        #pragma unroll
        for (int c = 0; c < 8; ++c) acc[a][c] = 0.f;

    for (int dc = 0; dc < 256; dc += 64) {
        #pragma unroll
        for (int k = 0; k < 8; ++k) {
            int idx = k * 256 + tid;
            int row = idx >> 4;                // nn or tt (128 rows)
            int d4  = idx & 15;                // 16 float4 across d-chunk
            float4 dv = *(const float4*)&D[((size_t)(n0 + row))*256 + dc + d4*4];
            float4 hv = *(const float4*)&H[((size_t)b*256 + t0 + row)*256 + dc + d4*4];
            Ds[d4*4+0][row] = dv.x; Ds[d4*4+1][row] = dv.y;
            Ds[d4*4+2][row] = dv.z; Ds[d4*4+3][row] = dv.w;
            Hs[d4*4+0][row] = hv.x; Hs[d4*4+1][row] = hv.y;
            Hs[d4*4+2][row] = hv.z; Hs[d4*4+3][row] = hv.w;
        }
        __syncthreads();
        #pragma unroll 4
        for (int dd = 0; dd < 64; ++dd) {
            float4 d0 = *(const float4*)&Ds[dd][8*tx];
            float4 d1 = *(const float4*)&Ds[dd][8*tx+4];
            float4 h0v = *(const float4*)&Hs[dd][8*ty];
            float4 h1v = *(const float4*)&Hs[dd][8*ty+4];
            float dv[8] = {d0.x,d0.y,d0.z,d0.w,d1.x,d1.y,d1.z,d1.w};
            float hv[8] = {h0v.x,h0v.y,h0v.z,h0v.w,h1v.x,h1v.y,h1v.z,h1v.w};
            #pragma unroll
            for (int a = 0; a < 8; ++a)
                #pragma unroll
                for (int c = 0; c < 8; ++c) acc[a][c] += dv[a] * hv[c];
        }
        __syncthreads();
    }
    #pragma unroll
    for (int a = 0; a < 8; ++a) {
        float* op = &out[((size_t)b*256 + n0 + 8*tx + a)*256 + t0 + 8*ty];
        *(float4*)(op)     = make_float4(acc[a][0], acc[a][1], acc[a][2], acc[a][3]);
        *(float4*)(op + 4) = make_float4(acc[a][4], acc[a][5], acc[a][6], acc[a][7]);
    }
}

// ---------------------------------------------------------------------------
extern "C" void kernel_launch(void* const* d_in, const int* in_sizes, int n_in,
                              void* d_out, int out_size, void* d_ws, size_t ws_size,
                              hipStream_t stream) {
    const float* y     = (const float*)d_in[0];
    const float* A     = (const float*)d_in[1];
    const float* D     = (const float*)d_in[2];
    const float* F     = (const float*)d_in[3];
    const float* lam1  = (const float*)d_in[4];
    const float* lam2  = (const float*)d_in[5];
    const float* alpha = (const float*)d_in[6];
    const float* h0    = (const float*)d_in[7];
    const float* U     = (const float*)d_in[8];
    float* out = (float*)d_out;
    float* ws  = (float*)d_ws;

    // ws layout (fp32-element offsets)
    const size_t oZ  = 0;           // Zh: 8.39M u32 packed fp16 (region 16.7M)
    const size_t oH  = 16777216;    // H fp32: 16.7M
    const size_t oWt = 33554432;
    const size_t oSt = 33619968;
    const size_t oPt = 33685504;
    const size_t oFD = 33751040;
    const size_t oG  = 33816576;
    const size_t oGD = 33882112;
    const size_t oAD = 33947648;
    const size_t oSh = 33964032;   // Sfrag u32 (32768)
    const size_t oPh = 33996800;   // Pfrag u32 (32768)

    u32*   Zh = (u32*)(ws + oZ);
    float* H  = ws + oH;
    float* Wt = ws + oWt; float* St = ws + oSt; float* Pt = ws + oPt;
    float* FD = ws + oFD; float* G  = ws + oG;  float* GD = ws + oGD;
    float* AD = ws + oAD;
    u32* Sfrag = (u32*)(ws + oSh);
    u32* Pfrag = (u32*)(ws + oPh);

    prep1<<<576, 256, 0, stream>>>(A, D, F, lam2, FD, G, AD);
    prep2<<<768, 256, 0, stream>>>(A, D, alpha, FD, G, AD, Pt, GD, Wt);
    prep3<<<256, 256, 0, stream>>>(D, GD, alpha, St);
    prep4<<<64, 256, 0, stream>>>(St, Pt, Sfrag, Pfrag);
    {
        dim3 g(256, 4);
        zgemm<<<g, 256, 0, stream>>>(y, Wt, Zh);
    }
    scan6<<<16, 512, 0, stream>>>(Sfrag, Pfrag, Zh, h0, U, lam1, lam2, alpha, H);
    {
        dim3 g(256, 4);
        ogemm<<<g, 256, 0, stream>>>(D, H, out);
    }
}